// Round 1
// baseline (419.584 us; speedup 1.0000x reference)
//
#include <hip/hip_runtime.h>
#include <math.h>

#define NPS 32          // patches per side
#define NN  (NPS*NPS)   // 1024 patches
#define LL  6           // levels
#define DD  512         // feature dim
#define NBR 29          // stencil size for radius 3.0

// Scale factor: d^-0.5 = 1/sqrt(512)
#define INV_SQRT_D 0.044194173824159216f

// Pass 1: per-row reciprocal-norm * d^-0.5.  One wave per row (512 floats).
__global__ __launch_bounds__(256) void ca_norm_kernel(const float* __restrict__ levels,
                                                      float* __restrict__ scale,
                                                      int rows) {
    int w    = (int)((blockIdx.x * (unsigned)blockDim.x + threadIdx.x) >> 6);
    int lane = threadIdx.x & 63;
    if (w >= rows) return;
    const float4* x4 = (const float4*)(levels + (size_t)w * DD);
    float4 a0 = x4[lane * 2];
    float4 a1 = x4[lane * 2 + 1];
    float s = a0.x*a0.x + a0.y*a0.y + a0.z*a0.z + a0.w*a0.w
            + a1.x*a1.x + a1.y*a1.y + a1.z*a1.z + a1.w*a1.w;
    #pragma unroll
    for (int off = 32; off; off >>= 1) s += __shfl_xor(s, off, 64);
    if (lane == 0) {
        float nrm = fmaxf(sqrtf(s), 1e-12f);
        scale[w] = INV_SQRT_D / nrm;
    }
}

// Pass 2: one wave per output row (b,i,l).  Online-softmax over the <=29
// unmasked neighbors (patch-grid distance <= 3).  Each neighbor vector is
// loaded exactly once; dot-product wave-reduced via shfl_xor.
__global__ __launch_bounds__(256) void ca_attn_kernel(const float* __restrict__ levels,
                                                      const float* __restrict__ scale,
                                                      float* __restrict__ out,
                                                      int rows) {
    // The 29 offsets with dh*dh + dw*dw <= 9:
    constexpr int dh[NBR] = {-3,
                             -2,-2,-2,-2,-2,
                             -1,-1,-1,-1,-1,
                              0, 0, 0, 0, 0, 0, 0,
                              1, 1, 1, 1, 1,
                              2, 2, 2, 2, 2,
                              3};
    constexpr int dw[NBR] = { 0,
                             -2,-1, 0, 1, 2,
                             -2,-1, 0, 1, 2,
                             -3,-2,-1, 0, 1, 2, 3,
                             -2,-1, 0, 1, 2,
                             -2,-1, 0, 1, 2,
                              0};

    int w    = (int)((blockIdx.x * (unsigned)blockDim.x + threadIdx.x) >> 6);
    int lane = threadIdx.x & 63;
    if (w >= rows) return;

    // row = (b*NN + i)*LL + l  ->  patch index i
    int i  = (w / LL) % NN;
    int ph = i >> 5;
    int pw = i & 31;

    const float4* xi4 = (const float4*)(levels + (size_t)w * DD);
    float4 a0 = xi4[lane * 2];
    float4 a1 = xi4[lane * 2 + 1];

    float m    = -INFINITY;
    float lsum = 0.0f;
    float acc0 = 0.f, acc1 = 0.f, acc2 = 0.f, acc3 = 0.f;
    float acc4 = 0.f, acc5 = 0.f, acc6 = 0.f, acc7 = 0.f;

    #pragma unroll
    for (int t = 0; t < NBR; ++t) {
        int hh = ph + dh[t];
        int ww = pw + dw[t];
        // wave-uniform branch (all lanes share the row) -> no divergence
        if ((unsigned)hh < (unsigned)NPS && (unsigned)ww < (unsigned)NPS) {
            int jrow = w + (dh[t] * NPS + dw[t]) * LL;   // same b, same l
            const float4* xj4 = (const float4*)(levels + (size_t)jrow * DD);
            float4 b0 = xj4[lane * 2];
            float4 b1 = xj4[lane * 2 + 1];
            float d = a0.x*b0.x + a0.y*b0.y + a0.z*b0.z + a0.w*b0.w
                    + a1.x*b1.x + a1.y*b1.y + a1.z*b1.z + a1.w*b1.w;
            #pragma unroll
            for (int off = 32; off; off >>= 1) d += __shfl_xor(d, off, 64);
            float s  = d * scale[jrow];
            float mn = fmaxf(m, s);
            float c  = __expf(m - mn);   // first valid iter: exp(-inf) = 0
            float p  = __expf(s - mn);
            lsum = lsum * c + p;
            acc0 = acc0 * c + p * b0.x;
            acc1 = acc1 * c + p * b0.y;
            acc2 = acc2 * c + p * b0.z;
            acc3 = acc3 * c + p * b0.w;
            acc4 = acc4 * c + p * b1.x;
            acc5 = acc5 * c + p * b1.y;
            acc6 = acc6 * c + p * b1.z;
            acc7 = acc7 * c + p * b1.w;
            m = mn;
        }
    }

    float inv = 1.0f / lsum;
    float4 o0 = make_float4(acc0 * inv, acc1 * inv, acc2 * inv, acc3 * inv);
    float4 o1 = make_float4(acc4 * inv, acc5 * inv, acc6 * inv, acc7 * inv);
    float4* o4 = (float4*)(out + (size_t)w * DD);
    o4[lane * 2]     = o0;
    o4[lane * 2 + 1] = o1;
}

extern "C" void kernel_launch(void* const* d_in, const int* in_sizes, int n_in,
                              void* d_out, int out_size, void* d_ws, size_t ws_size,
                              hipStream_t stream) {
    const float* levels = (const float*)d_in[0];
    // d_in[1] = non_local_mask: ignored — it is the fixed radius-3.0 stencil,
    // hardcoded as the 29-offset list above.
    float* out   = (float*)d_out;
    float* scale = (float*)d_ws;              // 49152 floats = 192 KB scratch

    int rows = in_sizes[0] / DD;              // b*n*l = 49152
    int waves_per_block = 4;                  // 256 threads = 4 waves
    int blocks = (rows + waves_per_block - 1) / waves_per_block;

    ca_norm_kernel<<<blocks, 256, 0, stream>>>(levels, scale, rows);
    ca_attn_kernel<<<blocks, 256, 0, stream>>>(levels, scale, out, rows);
}

// Round 2
// 310.258 us; speedup vs baseline: 1.3524x; 1.3524x over previous
//
#include <hip/hip_runtime.h>
#include <math.h>

#define NPS 32          // patches per side
#define NN  (NPS*NPS)   // 1024 patches
#define LL  6           // levels
#define DD  512         // feature dim
#define NBR 29          // stencil size for radius 3.0

// d^-0.5 = 1/sqrt(512)
#define INV_SQRT_D 0.044194173824159216f

// Fused kernel: one wave per output row (b,i,l).
//  - Neighbor norms recomputed in-wave (joint shuffle reduce of dot & ||x_j||^2)
//    -> no separate norm pass, no 100 MB extra HBM read.
//  - Row max of sim is EXACTLY the diagonal term ||x_i||/sqrt(d) (Cauchy-Schwarz,
//    diagonal always unmasked) -> plain exp accumulation, no online rescale.
//  - blockIdx swizzled so each XCD processes one batch b (rows/8 == 6144 == one
//    batch): zero cross-XCD data sharing, neighbor window stays in per-XCD L2.
__global__ __launch_bounds__(256) void ca_fused_kernel(const float* __restrict__ levels,
                                                       float* __restrict__ out,
                                                       int rows) {
    // The 29 offsets with dh*dh + dw*dw <= 9:
    constexpr int dh[NBR] = {-3,
                             -2,-2,-2,-2,-2,
                             -1,-1,-1,-1,-1,
                              0, 0, 0, 0, 0, 0, 0,
                              1, 1, 1, 1, 1,
                              2, 2, 2, 2, 2,
                              3};
    constexpr int dw[NBR] = { 0,
                             -2,-1, 0, 1, 2,
                             -2,-1, 0, 1, 2,
                             -3,-2,-1, 0, 1, 2, 3,
                             -2,-1, 0, 1, 2,
                             -2,-1, 0, 1, 2,
                              0};

    // XCD-aware swizzle: hardware round-robins blocks over 8 XCDs, so give
    // XCD x the contiguous block-chunk x -> XCD x handles batch x only.
    unsigned bk    = blockIdx.x;
    unsigned chunk = gridDim.x >> 3;               // 12288/8 = 1536
    unsigned vb    = (bk & 7) * chunk + (bk >> 3); // virtual block id
    int w    = (int)(vb * 4 + (threadIdx.x >> 6)); // 4 waves/block, row per wave
    int lane = threadIdx.x & 63;
    if (w >= rows) return;

    // row = (b*NN + i)*LL + l  ->  patch index i
    int i  = (w / LL) % NN;
    int ph = i >> 5;
    int pw = i & 31;

    const float4* xi4 = (const float4*)(levels + (size_t)w * DD);
    float4 a0 = xi4[lane * 2];
    float4 a1 = xi4[lane * 2 + 1];

    // Row max m = sim_ii = ||x_i|| / sqrt(d)  (exact row max; diagonal unmasked)
    float s2i = a0.x*a0.x + a0.y*a0.y + a0.z*a0.z + a0.w*a0.w
              + a1.x*a1.x + a1.y*a1.y + a1.z*a1.z + a1.w*a1.w;
    #pragma unroll
    for (int off = 32; off; off >>= 1) s2i += __shfl_xor(s2i, off, 64);
    float m = s2i * __frsqrt_rn(s2i) * INV_SQRT_D;   // = sqrt(s2i)*INV_SQRT_D

    float lsum = 0.0f;
    float acc0 = 0.f, acc1 = 0.f, acc2 = 0.f, acc3 = 0.f;
    float acc4 = 0.f, acc5 = 0.f, acc6 = 0.f, acc7 = 0.f;

    #pragma unroll
    for (int t = 0; t < NBR; ++t) {
        int hh = ph + dh[t];
        int ww = pw + dw[t];
        // wave-uniform branch (all lanes share the row) -> no divergence
        if ((unsigned)hh < (unsigned)NPS && (unsigned)ww < (unsigned)NPS) {
            int jrow = w + (dh[t] * NPS + dw[t]) * LL;   // same b, same l
            const float4* xj4 = (const float4*)(levels + (size_t)jrow * DD);
            float4 b0 = xj4[lane * 2];
            float4 b1 = xj4[lane * 2 + 1];
            // Joint reduce: dot(x_i,x_j) and ||x_j||^2 through one shuffle tree
            float d  = a0.x*b0.x + a0.y*b0.y + a0.z*b0.z + a0.w*b0.w
                     + a1.x*b1.x + a1.y*b1.y + a1.z*b1.z + a1.w*b1.w;
            float s2 = b0.x*b0.x + b0.y*b0.y + b0.z*b0.z + b0.w*b0.w
                     + b1.x*b1.x + b1.y*b1.y + b1.z*b1.z + b1.w*b1.w;
            #pragma unroll
            for (int off = 32; off; off >>= 1) {
                d  += __shfl_xor(d,  off, 64);
                s2 += __shfl_xor(s2, off, 64);
            }
            float s = d * __frsqrt_rn(s2) * INV_SQRT_D;  // sim_ij, <= m
            float p = __expf(s - m);                     // self term -> exp(0)=1
            lsum += p;
            acc0 += p * b0.x;
            acc1 += p * b0.y;
            acc2 += p * b0.z;
            acc3 += p * b0.w;
            acc4 += p * b1.x;
            acc5 += p * b1.y;
            acc6 += p * b1.z;
            acc7 += p * b1.w;
        }
    }

    float inv = 1.0f / lsum;
    float4 o0 = make_float4(acc0 * inv, acc1 * inv, acc2 * inv, acc3 * inv);
    float4 o1 = make_float4(acc4 * inv, acc5 * inv, acc6 * inv, acc7 * inv);
    float4* o4 = (float4*)(out + (size_t)w * DD);
    o4[lane * 2]     = o0;
    o4[lane * 2 + 1] = o1;
}

extern "C" void kernel_launch(void* const* d_in, const int* in_sizes, int n_in,
                              void* d_out, int out_size, void* d_ws, size_t ws_size,
                              hipStream_t stream) {
    const float* levels = (const float*)d_in[0];
    // d_in[1] = non_local_mask: fixed radius-3.0 stencil, hardcoded as the
    // 29-offset list above.
    float* out = (float*)d_out;

    int rows = in_sizes[0] / DD;              // b*n*l = 49152
    int blocks = (rows + 3) / 4;              // 4 waves/block, 1 row/wave = 12288

    ca_fused_kernel<<<blocks, 256, 0, stream>>>(levels, out, rows);
}